// Round 10
// baseline (87.054 us; speedup 1.0000x reference)
//
#include <hip/hip_runtime.h>

#define B_SZ 32
#define L_SZ 512
#define D_SZ 256
#define FRAMES_PER_WAVE 8
#define FRAMES_PER_BLOCK 32    // 4 waves x 8 frames

// clang-native vector types (required by __builtin_nontemporal_*)
typedef float f4 __attribute__((ext_vector_type(4)));
typedef int   i4 __attribute__((ext_vector_type(4)));

// Output-centric gather: wave owns 8 consecutive OUTPUT frames of batch b.
// Store side mimics the 6.2 TB/s fill: every frame stored unconditionally,
// dense, exactly once, in block order; pad frames fall out as mask==0 -> 0.
// Row lookup is all-register: ballot over the lane-scan + 2 shfl + 8-step
// walk of 3-bit packed durations. No LDS, no barriers, no conditional stores.
__global__ void __launch_bounds__(256)
lr_gather_kernel(const float* __restrict__ hidden,
                 const int* __restrict__ durations,
                 float* __restrict__ out,
                 int maxT, int chunks) {
    const int lane  = threadIdx.x & 63;
    const int wv    = threadIdx.x >> 6;
    const int bid   = blockIdx.x;
    const int b     = bid / chunks;             // consecutive bids sweep one batch
    const int chunk = bid - b * chunks;
    const int t0    = chunk * FRAMES_PER_BLOCK + wv * FRAMES_PER_WAVE;
    if (t0 >= maxT) return;                     // wave-uniform

    // duration row: lane i holds durs[8i .. 8i+7]
    const i4* drow = (const i4*)(durations + b * L_SZ);
    const i4 a = drow[lane * 2];
    const i4 c = drow[lane * 2 + 1];
    const int s = a.x + a.y + a.z + a.w + c.x + c.y + c.z + c.w;    // <= 56
    const int packed = a.x | (a.y << 3) | (a.z << 6) | (a.w << 9)
                     | (c.x << 12) | (c.y << 15) | (c.z << 18) | (c.w << 21);

    // inclusive scan of per-lane sums across the wave
    int incl = s;
    #pragma unroll
    for (int off = 1; off < 64; off <<= 1) {
        const int tt = __shfl_up(incl, off, 64);
        if (lane >= off) incl += tt;
    }
    const int ex = incl - s;    // exclusive prefix: start frame of lane's rows

    const float* hbase = hidden + (size_t)b * L_SZ * D_SZ;
    float*       obase = out    + (size_t)b * maxT * D_SZ;
    const f4 z = (f4){0.f, 0.f, 0.f, 0.f};

    #pragma unroll
    for (int f = 0; f < FRAMES_PER_WAVE; ++f) {
        const int t = t0 + f;
        if (t >= maxT) break;                   // wave-uniform
        const unsigned long long mask = __ballot(incl > t);
        f4 v = z;
        if (mask) {                             // t < total: find owning row
            const int l    = __ffsll(mask) - 1;        // first lane covering t
            const int base = __shfl(ex, l, 64);
            const int pk   = __shfl(packed, l, 64);
            int acc = base, r = 0;
            #pragma unroll
            for (int k = 0; k < 7; ++k) {       // count incl prefixes <= t
                acc += (pk >> (3 * k)) & 7;
                r += (acc <= t);
            }
            const int row = l * 8 + r;          // phoneme index for frame t
            v = *((const f4*)(hbase + (size_t)row * D_SZ) + lane);  // cached: d-fold reuse
        }
        __builtin_nontemporal_store(v, (f4*)(obase + (size_t)t * D_SZ) + lane);
    }
}

extern "C" void kernel_launch(void* const* d_in, const int* in_sizes, int n_in,
                              void* d_out, int out_size, void* d_ws, size_t ws_size,
                              hipStream_t stream) {
    const float* hidden = (const float*)d_in[0];
    const int* durations = (const int*)d_in[1];
    float* out = (float*)d_out;

    const int maxT   = out_size / (B_SZ * D_SZ);
    const int chunks = (maxT + FRAMES_PER_BLOCK - 1) / FRAMES_PER_BLOCK;

    lr_gather_kernel<<<B_SZ * chunks, 256, 0, stream>>>(hidden, durations, out,
                                                        maxT, chunks);
}